// Round 8
// baseline (745.846 us; speedup 1.0000x reference)
//
#include <hip/hip_runtime.h>
#include <math.h>

#define NN 25000
#define NE 100000

typedef _Float16 f16;
typedef _Float16 half8 __attribute__((ext_vector_type(8)));
typedef float f32x4 __attribute__((ext_vector_type(4)));

// ---------------- one-time weight prep (merged) ----------------
// [0, 39936): transposed fp32 weights T ; [39936, 306176): Wf16 (65 slabs of
// [64 o][64 k] fp16; slabs 0..63 = We3 verbatim, slab 64 = be3 transposed).
__global__ __launch_bounds__(256) void prep_all(
    const float* __restrict__ Wn1, const float* __restrict__ Wn2,
    const float* __restrict__ Wn3, const float* __restrict__ We1,
    const float* __restrict__ We2, const float* __restrict__ Wih,
    const float* __restrict__ Whh, const float* __restrict__ We3,
    const float* __restrict__ be3, float* __restrict__ T,
    f16* __restrict__ Wf16)
{
    int f = blockIdx.x * 256 + threadIdx.x;          // 0 .. 306175
    if (f < 39936) {
        if (f < 2048)       { int j = f;         T[f] = Wn1[(j & 63) * 32 + (j >> 6)]; }
        else if (f < 6144)  { int j = f - 2048;  T[f] = Wn2[(j & 63) * 64 + (j >> 6)]; }
        else if (f < 10240) { int j = f - 6144;  T[f] = Wn3[(j & 63) * 64 + (j >> 6)]; }
        else if (f < 11264) { int j = f - 10240; T[f] = We1[(j & 63) * 16 + (j >> 6)]; }
        else if (f < 15360) { int j = f - 11264; T[f] = We2[(j & 63) * 64 + (j >> 6)]; }
        else if (f < 27648) { int j = f - 15360; T[f] = Wih[(j % 192) * 64 + (j / 192)]; }
        else                { int j = f - 27648; T[f] = Whh[(j % 192) * 64 + (j / 192)]; }
    } else {
        int g = f - 39936;                           // 0 .. 266239
        if (g < 262144) Wf16[g] = (f16)We3[g];
        else {
            int j = g - 262144; int o = (j >> 6), k = j & 63;
            Wf16[g] = (f16)be3[k * 64 + o];
        }
    }
}

// ---------------- node MLP: 8 nodes per wave (weights reused x8) ----------------
__global__ __launch_bounds__(256) void node_mlp(
    const float* __restrict__ x, const float* __restrict__ T,
    const float* __restrict__ bn1, const float* __restrict__ bn2,
    const float* __restrict__ bn3,
    float* __restrict__ hbuf, f16* __restrict__ h16, float* __restrict__ aggr)
{
    __shared__ float sx[4][8][32];
    __shared__ float sh1[4][8][64];
    const float* Wn1T = T;            // [32][64]
    const float* Wn2T = T + 2048;     // [64][64]
    const float* Wn3T = T + 6144;     // [64][64]
    int w = threadIdx.x >> 6, lane = threadIdx.x & 63;
    int n0 = blockIdx.x * 32 + w * 8;
    if (n0 >= NN) return;             // NN%8==0 -> wave's 8 nodes all valid or none
    #pragma unroll
    for (int jj = 0; jj < 4; ++jj) {  // 8 nodes x 32 floats = 4 per lane
        int f = jj * 64 + lane;
        sx[w][f >> 5][f & 31] = x[(size_t)(n0 + (f >> 5)) * 32 + (f & 31)];
    }
    float a[8];
    #pragma unroll
    for (int j = 0; j < 8; ++j) a[j] = bn1[lane];
    for (int i = 0; i < 32; i += 4) {
        float4 bb[8];
        #pragma unroll
        for (int j = 0; j < 8; ++j) bb[j] = *(const float4*)&sx[w][j][i];
        #pragma unroll
        for (int ii = 0; ii < 4; ++ii) {
            float wv = Wn1T[(i + ii) * 64 + lane];
            #pragma unroll
            for (int j = 0; j < 8; ++j) a[j] += ((const float*)&bb[j])[ii] * wv;
        }
    }
    #pragma unroll
    for (int j = 0; j < 8; ++j) { sh1[w][j][lane] = fmaxf(a[j], 0.f); a[j] = bn2[lane]; }
    for (int i = 0; i < 64; i += 4) {
        float4 bb[8];
        #pragma unroll
        for (int j = 0; j < 8; ++j) bb[j] = *(const float4*)&sh1[w][j][i];
        #pragma unroll
        for (int ii = 0; ii < 4; ++ii) {
            float wv = Wn2T[(i + ii) * 64 + lane];
            #pragma unroll
            for (int j = 0; j < 8; ++j) a[j] += ((const float*)&bb[j])[ii] * wv;
        }
    }
    // in-wave: all reads of sh1 above complete (program order) before overwrite
    #pragma unroll
    for (int j = 0; j < 8; ++j) { sh1[w][j][lane] = fmaxf(a[j], 0.f); a[j] = bn3[lane]; }
    for (int i = 0; i < 64; i += 4) {
        float4 bb[8];
        #pragma unroll
        for (int j = 0; j < 8; ++j) bb[j] = *(const float4*)&sh1[w][j][i];
        #pragma unroll
        for (int ii = 0; ii < 4; ++ii) {
            float wv = Wn3T[(i + ii) * 64 + lane];
            #pragma unroll
            for (int j = 0; j < 8; ++j) a[j] += ((const float*)&bb[j])[ii] * wv;
        }
    }
    #pragma unroll
    for (int j = 0; j < 8; ++j) {
        size_t idx = (size_t)(n0 + j) * 64 + lane;
        hbuf[idx] = a[j];
        h16[idx]  = (f16)a[j];
        aggr[idx] = 0.f;              // zero aggr for layer 0 (no memset launch)
    }
}

// ---------------- edge MLP: 8 edges per wave ----------------
__global__ __launch_bounds__(256) void edge_mlp(
    const float* __restrict__ ea, const float* __restrict__ T,
    const float* __restrict__ be1, const float* __restrict__ be2,
    f16* __restrict__ ew16)
{
    __shared__ float sa[4][8][16];
    __shared__ float st[4][8][64];
    const float* We1T = T + 10240;    // [16][64]
    const float* We2T = T + 11264;    // [64][64]
    int w = threadIdx.x >> 6, lane = threadIdx.x & 63;
    int e0 = blockIdx.x * 32 + w * 8;
    if (e0 >= NE) return;             // NE%32==0
    #pragma unroll
    for (int jj = 0; jj < 2; ++jj) {  // 8 edges x 16 floats = 2 per lane
        int f = jj * 64 + lane;
        sa[w][f >> 4][f & 15] = ea[(size_t)(e0 + (f >> 4)) * 16 + (f & 15)];
    }
    float a[8];
    #pragma unroll
    for (int j = 0; j < 8; ++j) a[j] = be1[lane];
    for (int i = 0; i < 16; i += 4) {
        float4 bb[8];
        #pragma unroll
        for (int j = 0; j < 8; ++j) bb[j] = *(const float4*)&sa[w][j][i];
        #pragma unroll
        for (int ii = 0; ii < 4; ++ii) {
            float wv = We1T[(i + ii) * 64 + lane];
            #pragma unroll
            for (int j = 0; j < 8; ++j) a[j] += ((const float*)&bb[j])[ii] * wv;
        }
    }
    #pragma unroll
    for (int j = 0; j < 8; ++j) { st[w][j][lane] = fmaxf(a[j], 0.f); a[j] = be2[lane]; }
    for (int i = 0; i < 64; i += 4) {
        float4 bb[8];
        #pragma unroll
        for (int j = 0; j < 8; ++j) bb[j] = *(const float4*)&st[w][j][i];
        #pragma unroll
        for (int ii = 0; ii < 4; ++ii) {
            float wv = We2T[(i + ii) * 64 + lane];
            #pragma unroll
            for (int j = 0; j < 8; ++j) a[j] += ((const float*)&bb[j])[ii] * wv;
        }
    }
    #pragma unroll
    for (int j = 0; j < 8; ++j)
        ew16[(size_t)(e0 + j) * 64 + lane] = (f16)fmaxf(a[j], 0.f);
}

// ---------------- message GEMM (MFMA f16) + scatter ----------------
__device__ __forceinline__ half8 splat8(f16 v)
{ half8 r = { v, v, v, v, v, v, v, v }; return r; }

// msg[E,64] = P[E,4160] @ [Wf16; be3T], P[e, i*64+k] = h16[src_e,i]*ew16[e,k].
// Round-7 ring/swizzle/prefetch scheme, re-tiled: block = 128 edges, 2 waves;
// wave = 64 edges (4 M-subtiles, acc[4][4]) -> B-frag LDS reads amortized
// 4 MFMA per read (was 2), halving per-CU LDS read traffic (the round-7
// dominant term). Same XOR swizzle pair; prefetch depth 2 pairs unchanged.
__global__ __launch_bounds__(128, 2) void msg_mfma(
    const f16* __restrict__ h16, const f16* __restrict__ ew16,
    const f16* __restrict__ Wf16, const int* __restrict__ edge_index,
    float* __restrict__ aggr)
{
    __shared__ f16 sh_h[128][72];      // 18432 B
    __shared__ f16 sh_ring[4][4096];   // 32768 B: ew staging, then 4-slab B ring
    __shared__ int sh_dst[128];
    int t = threadIdx.x, lane = t & 63, wv = t >> 6;
    int e0 = blockIdx.x * 128;
    char* ringc = (char*)&sh_ring[0][0];

    // issue slabs 0,1 global loads first (hide under gather)
    const uint4* gW = (const uint4*)Wf16;            // 512 uint4 per 8KB slab
    uint4 r[8];
    #pragma unroll
    for (int q = 0; q < 4; ++q) r[q]     = gW[q * 128 + t];        // slab 0
    #pragma unroll
    for (int q = 0; q < 4; ++q) r[4 + q] = gW[512 + q * 128 + t];  // slab 1

    {   // gather: 1 thread per edge-row (128 B h + 128 B ew each)
        int e = e0 + t;
        bool valid = e < NE;
        int ec = valid ? e : NE - 1;
        int src = edge_index[ec];
        const uint4* hp = (const uint4*)(h16 + (size_t)src * 64);
        const uint4* ep = (const uint4*)(ew16 + (size_t)ec * 64);
        uint4 z = make_uint4(0u, 0u, 0u, 0u);
        int rb = t * 128, key = (t & 7) << 4;        // ew: stride 128B + XOR swz
        #pragma unroll
        for (int q = 0; q < 8; ++q) {
            uint4 hq = hp[q];
            uint4 gq = valid ? ep[q] : z;
            *(uint4*)&sh_h[t][q * 8] = hq;
            *(uint4*)(ringc + rb + ((q * 16) ^ key)) = gq;
        }
        sh_dst[t] = valid ? edge_index[NE + e] : -1;
    }

    int r16 = lane & 15, kq = lane >> 4;
    int rowm[4];
    #pragma unroll
    for (int m = 0; m < 4; ++m) rowm[m] = wv * 64 + m * 16 + r16;

    // in-wave hoist of K-invariant ew fragments (wave reads rows it wrote)
    half8 ev0[4], ev1[4];
    #pragma unroll
    for (int m = 0; m < 4; ++m) {
        int key = (rowm[m] & 7) << 4;                // = (r16&7)<<4 for all m
        ev0[m] = *(const half8*)(ringc + rowm[m] * 128 + ((kq * 16) ^ key));
        ev1[m] = *(const half8*)(ringc + rowm[m] * 128 + ((64 + kq * 16) ^ key));
    }

    __syncthreads();                  // barrier1: hoists done, ring free, dst visible

    int dsw[8];
    #pragma unroll
    for (int q = 0; q < 8; ++q) {
        int d = q * 2048 + t * 16;                   // pair = 16KB
        dsw[q] = d ^ (((d >> 7) & 7) << 4);
    }

    // write pair0 (slabs 0,1); issue slabs 2,3
    #pragma unroll
    for (int q = 0; q < 8; ++q) *(uint4*)(ringc + dsw[q]) = r[q];
    #pragma unroll
    for (int q = 0; q < 4; ++q) r[q]     = gW[2 * 512 + q * 128 + t];
    #pragma unroll
    for (int q = 0; q < 4; ++q) r[4 + q] = gW[3 * 512 + q * 128 + t];
    __syncthreads();                  // barrier2: pair0 ready

    f32x4 acc[4][4];
    #pragma unroll
    for (int m = 0; m < 4; ++m)
        #pragma unroll
        for (int n = 0; n < 4; ++n) acc[m][n] = (f32x4){0, 0, 0, 0};

    int swzA = (kq << 4) ^ ((r16 & 7) << 4);
    int swzB = ((kq << 4) | 64) ^ ((r16 & 7) << 4);

    for (int i8 = 0; i8 < 8; ++i8) {                 // 8 h-chunks x 4 windows
        half8 hM[4];
        #pragma unroll
        for (int m = 0; m < 4; ++m) hM[m] = *(const half8*)&sh_h[rowm[m]][i8 * 8];
        #pragma unroll
        for (int w2 = 0; w2 < 4; ++w2) {             // window: 2 slabs, 64 MFMA
            const char* pairR = ringc + (w2 & 1) * 16384 + r16 * 128;
            #pragma unroll
            for (int s = 0; s < 2; ++s) {
                const char* bb = pairR + s * 8192;
                half8 b00 = *(const half8*)(bb + 0    + swzA);
                half8 b01 = *(const half8*)(bb + 0    + swzB);
                half8 b10 = *(const half8*)(bb + 2048 + swzA);
                half8 b11 = *(const half8*)(bb + 2048 + swzB);
                half8 b20 = *(const half8*)(bb + 4096 + swzA);
                half8 b21 = *(const half8*)(bb + 4096 + swzB);
                half8 b30 = *(const half8*)(bb + 6144 + swzA);
                half8 b31 = *(const half8*)(bb + 6144 + swzB);
                #pragma unroll
                for (int m = 0; m < 4; ++m) {
                    f16 hs = hM[m][w2 * 2 + s];      // static index
                    half8 a0 = ev0[m] * splat8(hs);
                    half8 a1 = ev1[m] * splat8(hs);
                    acc[m][0] = __builtin_amdgcn_mfma_f32_16x16x32_f16(a0, b00, acc[m][0], 0, 0, 0);
                    acc[m][0] = __builtin_amdgcn_mfma_f32_16x16x32_f16(a1, b01, acc[m][0], 0, 0, 0);
                    acc[m][1] = __builtin_amdgcn_mfma_f32_16x16x32_f16(a0, b10, acc[m][1], 0, 0, 0);
                    acc[m][1] = __builtin_amdgcn_mfma_f32_16x16x32_f16(a1, b11, acc[m][1], 0, 0, 0);
                    acc[m][2] = __builtin_amdgcn_mfma_f32_16x16x32_f16(a0, b20, acc[m][2], 0, 0, 0);
                    acc[m][2] = __builtin_amdgcn_mfma_f32_16x16x32_f16(a1, b21, acc[m][2], 0, 0, 0);
                    acc[m][3] = __builtin_amdgcn_mfma_f32_16x16x32_f16(a0, b30, acc[m][3], 0, 0, 0);
                    acc[m][3] = __builtin_amdgcn_mfma_f32_16x16x32_f16(a1, b31, acc[m][3], 0, 0, 0);
                }
            }
            // stage next pair (regs hold slabs 2jw+2, 2jw+3); issue pair jw+2
            char* wb = ringc + ((w2 + 1) & 1) * 16384;
            #pragma unroll
            for (int q = 0; q < 8; ++q) *(uint4*)(wb + dsw[q]) = r[q];
            int jw = i8 * 4 + w2;
            int sA = jw * 2 + 4; if (sA > 64) sA = 64;   // slab 64 = bias slab
            int sB = jw * 2 + 5; if (sB > 64) sB = 64;
            #pragma unroll
            for (int q = 0; q < 4; ++q) r[q]     = gW[(size_t)sA * 512 + q * 128 + t];
            #pragma unroll
            for (int q = 0; q < 4; ++q) r[4 + q] = gW[(size_t)sB * 512 + q * 128 + t];
            __syncthreads();
        }
    }

    {   // bias slab (64) sits in pair0 half0: A = h16 rows, B = be3T
        const char* bb = ringc + r16 * 128;
        half8 b00 = *(const half8*)(bb + 0    + swzA);
        half8 b01 = *(const half8*)(bb + 0    + swzB);
        half8 b10 = *(const half8*)(bb + 2048 + swzA);
        half8 b11 = *(const half8*)(bb + 2048 + swzB);
        half8 b20 = *(const half8*)(bb + 4096 + swzA);
        half8 b21 = *(const half8*)(bb + 4096 + swzB);
        half8 b30 = *(const half8*)(bb + 6144 + swzA);
        half8 b31 = *(const half8*)(bb + 6144 + swzB);
        #pragma unroll
        for (int m = 0; m < 4; ++m) {
            half8 a0 = *(const half8*)&sh_h[rowm[m]][kq * 8];
            half8 a1 = *(const half8*)&sh_h[rowm[m]][32 + kq * 8];
            acc[m][0] = __builtin_amdgcn_mfma_f32_16x16x32_f16(a0, b00, acc[m][0], 0, 0, 0);
            acc[m][0] = __builtin_amdgcn_mfma_f32_16x16x32_f16(a1, b01, acc[m][0], 0, 0, 0);
            acc[m][1] = __builtin_amdgcn_mfma_f32_16x16x32_f16(a0, b10, acc[m][1], 0, 0, 0);
            acc[m][1] = __builtin_amdgcn_mfma_f32_16x16x32_f16(a1, b11, acc[m][1], 0, 0, 0);
            acc[m][2] = __builtin_amdgcn_mfma_f32_16x16x32_f16(a0, b20, acc[m][2], 0, 0, 0);
            acc[m][2] = __builtin_amdgcn_mfma_f32_16x16x32_f16(a1, b21, acc[m][2], 0, 0, 0);
            acc[m][3] = __builtin_amdgcn_mfma_f32_16x16x32_f16(a0, b30, acc[m][3], 0, 0, 0);
            acc[m][3] = __builtin_amdgcn_mfma_f32_16x16x32_f16(a1, b31, acc[m][3], 0, 0, 0);
        }
    }

    // scatter: C/D layout col=lane&15, row=(lane>>4)*4+reg  [m89-verified]
    #pragma unroll
    for (int m = 0; m < 4; ++m) {
        #pragma unroll
        for (int reg = 0; reg < 4; ++reg) {
            int e_l = wv * 64 + m * 16 + kq * 4 + reg;
            int d = sh_dst[e_l];
            if (d >= 0) {
                float* ap = aggr + (size_t)d * 64 + r16;
                atomicAdd(ap,      acc[m][0][reg]);
                atomicAdd(ap + 16, acc[m][1][reg]);
                atomicAdd(ap + 32, acc[m][2][reg]);
                atomicAdd(ap + 48, acc[m][3][reg]);
            }
        }
    }
}

// ---------------- fused root-term + GRU step: 8 nodes per wave ----------------
// hid buffer eliminated (hidden==hbuf after layer 0; ==0 at layer 0).
// Zeroes aggr in-place for the next layer. LDS broadcasts as float4.
__global__ __launch_bounds__(256) void gru_kernel(
    float* __restrict__ aggr, float* __restrict__ hbuf, f16* __restrict__ h16,
    const float* __restrict__ root, const float* __restrict__ cbias,
    const float* __restrict__ T, const float* __restrict__ bih,
    const float* __restrict__ bhh, float* __restrict__ out2, int first)
{
    __shared__ float sm_h[4][8][64];
    __shared__ float sm_m[4][8][64];
    const float* WihT = T + 15360;    // [64][192]
    const float* WhhT = T + 27648;    // [64][192]
    int w = threadIdx.x >> 6, lane = threadIdx.x & 63;
    int n0 = blockIdx.x * 32 + w * 8;
    if (n0 >= NN) return;             // NN%8==0

    float hv[8], m[8];
    #pragma unroll
    for (int j = 0; j < 8; ++j) {
        size_t idx = (size_t)(n0 + j) * 64 + lane;
        hv[j] = hbuf[idx];
        sm_h[w][j][lane] = hv[j];
        m[j] = aggr[idx] + cbias[lane];
        aggr[idx] = 0.f;              // ready for next layer's atomics
    }
    for (int i = 0; i < 64; i += 4) { // m += h @ root
        float4 bb[8];
        #pragma unroll
        for (int j = 0; j < 8; ++j) bb[j] = *(const float4*)&sm_h[w][j][i];
        #pragma unroll
        for (int ii = 0; ii < 4; ++ii) {
            float rv = root[(i + ii) * 64 + lane];
            #pragma unroll
            for (int j = 0; j < 8; ++j) m[j] += ((const float*)&bb[j])[ii] * rv;
        }
    }
    #pragma unroll
    for (int j = 0; j < 8; ++j) sm_m[w][j][lane] = m[j];

    float gr[8], gz[8], gn[8], hr[8], hz[8], hn[8];
    #pragma unroll
    for (int j = 0; j < 8; ++j) {
        gr[j] = bih[lane]; gz[j] = bih[64 + lane]; gn[j] = bih[128 + lane];
        hr[j] = bhh[lane]; hz[j] = bhh[64 + lane]; hn[j] = bhh[128 + lane];
    }
    for (int i = 0; i < 64; i += 4) {
        float4 bm[8], bh[8];
        #pragma unroll
        for (int j = 0; j < 8; ++j) {
            bm[j] = *(const float4*)&sm_m[w][j][i];
            bh[j] = *(const float4*)&sm_h[w][j][i];
        }
        #pragma unroll
        for (int ii = 0; ii < 4; ++ii) {
            float wr = WihT[(i + ii) * 192 + lane];
            float wz = WihT[(i + ii) * 192 + 64 + lane];
            float wn = WihT[(i + ii) * 192 + 128 + lane];
            #pragma unroll
            for (int j = 0; j < 8; ++j) {
                float mv = ((const float*)&bm[j])[ii];
                gr[j] += mv * wr; gz[j] += mv * wz; gn[j] += mv * wn;
            }
            if (!first) {
                float vr = WhhT[(i + ii) * 192 + lane];
                float vz = WhhT[(i + ii) * 192 + 64 + lane];
                float vn = WhhT[(i + ii) * 192 + 128 + lane];
                #pragma unroll
                for (int j = 0; j < 8; ++j) {
                    float dv = ((const float*)&bh[j])[ii];
                    hr[j] += dv * vr; hz[j] += dv * vz; hn[j] += dv * vn;
                }
            }
        }
    }

    #pragma unroll
    for (int j = 0; j < 8; ++j) {
        float r  = 1.f / (1.f + expf(-(gr[j] + hr[j])));
        float z  = 1.f / (1.f + expf(-(gz[j] + hz[j])));
        float nv = tanhf(gn[j] + r * hn[j]);
        float dvv = first ? 0.f : hv[j];
        float outv = (1.f - z) * nv + z * dvv;
        size_t idx = (size_t)(n0 + j) * 64 + lane;
        hbuf[idx] = outv;
        h16[idx]  = (f16)outv;
        if (out2) out2[idx] = outv;
    }
}

extern "C" void kernel_launch(void* const* d_in, const int* in_sizes, int n_in,
                              void* d_out, int out_size, void* d_ws, size_t ws_size,
                              hipStream_t stream)
{
    const float* x   = (const float*)d_in[0];
    const float* ea  = (const float*)d_in[1];
    const float* Wn1 = (const float*)d_in[2];  const float* bn1 = (const float*)d_in[3];
    const float* Wn2 = (const float*)d_in[4];  const float* bn2 = (const float*)d_in[5];
    const float* Wn3 = (const float*)d_in[6];  const float* bn3 = (const float*)d_in[7];
    const float* We1 = (const float*)d_in[8];  const float* be1 = (const float*)d_in[9];
    const float* We2 = (const float*)d_in[10]; const float* be2 = (const float*)d_in[11];
    const float* We3 = (const float*)d_in[12]; const float* be3 = (const float*)d_in[13];
    const float* roots = (const float*)d_in[14];
    const float* cb    = (const float*)d_in[15];
    const float* Wih = (const float*)d_in[16]; const float* Whh = (const float*)d_in[17];
    const float* bih = (const float*)d_in[18]; const float* bhh = (const float*)d_in[19];
    const int*   ei  = (const int*)d_in[20];

    // ws layout: fp32 region then fp16 region (16B-aligned), ~29.5 MB total
    float* ws   = (float*)d_ws;
    float* hbuf = ws;                               // N*64
    float* aggr = hbuf + (size_t)NN * 64;           // N*64
    float* Tbuf = aggr + (size_t)NN * 64;           // 39936 (pad to 40960)
    f16*   h16  = (f16*)(ws + 2 * (size_t)NN * 64 + 40960);   // N*64
    f16*   ew16 = h16  + (size_t)NN * 64;                     // E*64
    f16*   Wf16 = ew16 + (size_t)NE * 64;                     // 65*4096

    prep_all<<<(306176) / 256, 256, 0, stream>>>(Wn1, Wn2, Wn3, We1, We2,
                                                 Wih, Whh, We3, be3, Tbuf, Wf16);
    node_mlp<<<(NN + 31) / 32, 256, 0, stream>>>(x, Tbuf, bn1, bn2, bn3,
                                                 hbuf, h16, aggr);
    edge_mlp<<<NE / 32, 256, 0, stream>>>(ea, Tbuf, be1, be2, ew16);

    for (int l = 0; l < 3; ++l) {
        msg_mfma<<<(NE + 127) / 128, 128, 0, stream>>>(h16, ew16, Wf16, ei, aggr);
        gru_kernel<<<(NN + 31) / 32, 256, 0, stream>>>(aggr, hbuf, h16,
            roots + (size_t)l * 4096, cb + (size_t)l * 64,
            Tbuf, bih, bhh, (l == 2) ? (float*)d_out : nullptr, (l == 0) ? 1 : 0);
    }
}

// Round 9
// 409.426 us; speedup vs baseline: 1.8217x; 1.8217x over previous
//
#include <hip/hip_runtime.h>
#include <math.h>

#define NN 25000
#define NE 100000

typedef _Float16 f16;
typedef _Float16 half8 __attribute__((ext_vector_type(8)));
typedef float f32x4 __attribute__((ext_vector_type(4)));

// ---------------- one-time weight prep (merged) ----------------
// [0,15360): transposed fp32 T (Wn1T,Wn2T,Wn3T,We1T,We2T)
// then Wf16 (266240), root16 3x[64 o][64 i] f16, Wih16 [192][64], Whh16 [192][64]
__global__ __launch_bounds__(256) void prep_all(
    const float* __restrict__ Wn1, const float* __restrict__ Wn2,
    const float* __restrict__ Wn3, const float* __restrict__ We1,
    const float* __restrict__ We2, const float* __restrict__ Wih,
    const float* __restrict__ Whh, const float* __restrict__ We3,
    const float* __restrict__ be3, const float* __restrict__ roots,
    float* __restrict__ T, f16* __restrict__ Wf16, f16* __restrict__ root16,
    f16* __restrict__ Wih16, f16* __restrict__ Whh16)
{
    int f = blockIdx.x * 256 + threadIdx.x;          // 0 .. 318463
    if (f >= 318464) return;
    if (f < 15360) {
        if (f < 2048)       { int j = f;         T[f] = Wn1[(j & 63) * 32 + (j >> 6)]; }
        else if (f < 6144)  { int j = f - 2048;  T[f] = Wn2[(j & 63) * 64 + (j >> 6)]; }
        else if (f < 10240) { int j = f - 6144;  T[f] = Wn3[(j & 63) * 64 + (j >> 6)]; }
        else if (f < 11264) { int j = f - 10240; T[f] = We1[(j & 63) * 16 + (j >> 6)]; }
        else                { int j = f - 11264; T[f] = We2[(j & 63) * 64 + (j >> 6)]; }
    } else {
        int g = f - 15360;
        if (g < 266240) {
            if (g < 262144) Wf16[g] = (f16)We3[g];
            else {
                int j = g - 262144; int o = (j >> 6), k = j & 63;
                Wf16[g] = (f16)be3[k * 64 + o];
            }
        } else {
            int g2 = g - 266240;
            if (g2 < 12288) {                        // root16[l][o][i] = roots[l][i][o]
                int l = g2 >> 12, j = g2 & 4095, o = j >> 6, i = j & 63;
                root16[g2] = (f16)roots[l * 4096 + i * 64 + o];
            } else if (g2 < 24576) Wih16[g2 - 12288] = (f16)Wih[g2 - 12288];
            else                   Whh16[g2 - 24576] = (f16)Whh[g2 - 24576];
        }
    }
}

// ---------------- node MLP: 8 nodes per wave ----------------
__global__ __launch_bounds__(256) void node_mlp(
    const float* __restrict__ x, const float* __restrict__ T,
    const float* __restrict__ bn1, const float* __restrict__ bn2,
    const float* __restrict__ bn3,
    float* __restrict__ hbuf, f16* __restrict__ h16, float* __restrict__ aggr)
{
    __shared__ float sx[4][8][32];
    __shared__ float sh1[4][8][64];
    const float* Wn1T = T;            // [32][64]
    const float* Wn2T = T + 2048;     // [64][64]
    const float* Wn3T = T + 6144;     // [64][64]
    int w = threadIdx.x >> 6, lane = threadIdx.x & 63;
    int n0 = blockIdx.x * 32 + w * 8;
    if (n0 >= NN) return;             // NN%8==0
    #pragma unroll
    for (int jj = 0; jj < 4; ++jj) {
        int f = jj * 64 + lane;
        sx[w][f >> 5][f & 31] = x[(size_t)(n0 + (f >> 5)) * 32 + (f & 31)];
    }
    float a[8];
    #pragma unroll
    for (int j = 0; j < 8; ++j) a[j] = bn1[lane];
    for (int i = 0; i < 32; i += 4) {
        float4 bb[8];
        #pragma unroll
        for (int j = 0; j < 8; ++j) bb[j] = *(const float4*)&sx[w][j][i];
        #pragma unroll
        for (int ii = 0; ii < 4; ++ii) {
            float wv = Wn1T[(i + ii) * 64 + lane];
            #pragma unroll
            for (int j = 0; j < 8; ++j) a[j] += ((const float*)&bb[j])[ii] * wv;
        }
    }
    #pragma unroll
    for (int j = 0; j < 8; ++j) { sh1[w][j][lane] = fmaxf(a[j], 0.f); a[j] = bn2[lane]; }
    for (int i = 0; i < 64; i += 4) {
        float4 bb[8];
        #pragma unroll
        for (int j = 0; j < 8; ++j) bb[j] = *(const float4*)&sh1[w][j][i];
        #pragma unroll
        for (int ii = 0; ii < 4; ++ii) {
            float wv = Wn2T[(i + ii) * 64 + lane];
            #pragma unroll
            for (int j = 0; j < 8; ++j) a[j] += ((const float*)&bb[j])[ii] * wv;
        }
    }
    #pragma unroll
    for (int j = 0; j < 8; ++j) { sh1[w][j][lane] = fmaxf(a[j], 0.f); a[j] = bn3[lane]; }
    for (int i = 0; i < 64; i += 4) {
        float4 bb[8];
        #pragma unroll
        for (int j = 0; j < 8; ++j) bb[j] = *(const float4*)&sh1[w][j][i];
        #pragma unroll
        for (int ii = 0; ii < 4; ++ii) {
            float wv = Wn3T[(i + ii) * 64 + lane];
            #pragma unroll
            for (int j = 0; j < 8; ++j) a[j] += ((const float*)&bb[j])[ii] * wv;
        }
    }
    #pragma unroll
    for (int j = 0; j < 8; ++j) {
        size_t idx = (size_t)(n0 + j) * 64 + lane;
        hbuf[idx] = a[j];
        h16[idx]  = (f16)a[j];
        aggr[idx] = 0.f;
    }
}

// ---------------- edge MLP: 8 edges per wave ----------------
__global__ __launch_bounds__(256) void edge_mlp(
    const float* __restrict__ ea, const float* __restrict__ T,
    const float* __restrict__ be1, const float* __restrict__ be2,
    f16* __restrict__ ew16)
{
    __shared__ float sa[4][8][16];
    __shared__ float st[4][8][64];
    const float* We1T = T + 10240;    // [16][64]
    const float* We2T = T + 11264;    // [64][64]
    int w = threadIdx.x >> 6, lane = threadIdx.x & 63;
    int e0 = blockIdx.x * 32 + w * 8;
    if (e0 >= NE) return;
    #pragma unroll
    for (int jj = 0; jj < 2; ++jj) {
        int f = jj * 64 + lane;
        sa[w][f >> 4][f & 15] = ea[(size_t)(e0 + (f >> 4)) * 16 + (f & 15)];
    }
    float a[8];
    #pragma unroll
    for (int j = 0; j < 8; ++j) a[j] = be1[lane];
    for (int i = 0; i < 16; i += 4) {
        float4 bb[8];
        #pragma unroll
        for (int j = 0; j < 8; ++j) bb[j] = *(const float4*)&sa[w][j][i];
        #pragma unroll
        for (int ii = 0; ii < 4; ++ii) {
            float wv = We1T[(i + ii) * 64 + lane];
            #pragma unroll
            for (int j = 0; j < 8; ++j) a[j] += ((const float*)&bb[j])[ii] * wv;
        }
    }
    #pragma unroll
    for (int j = 0; j < 8; ++j) { st[w][j][lane] = fmaxf(a[j], 0.f); a[j] = be2[lane]; }
    for (int i = 0; i < 64; i += 4) {
        float4 bb[8];
        #pragma unroll
        for (int j = 0; j < 8; ++j) bb[j] = *(const float4*)&st[w][j][i];
        #pragma unroll
        for (int ii = 0; ii < 4; ++ii) {
            float wv = We2T[(i + ii) * 64 + lane];
            #pragma unroll
            for (int j = 0; j < 8; ++j) a[j] += ((const float*)&bb[j])[ii] * wv;
        }
    }
    #pragma unroll
    for (int j = 0; j < 8; ++j)
        ew16[(size_t)(e0 + j) * 64 + lane] = (f16)fmaxf(a[j], 0.f);
}

// ---------------- message GEMM (MFMA f16) + scatter — round-7 version ----------------
__device__ __forceinline__ half8 splat8(f16 v)
{ half8 r = { v, v, v, v, v, v, v, v }; return r; }

__device__ __forceinline__ void mfma_block(
    const char* bb, int swzA, int swzB,
    half8 aA0, half8 aA1, half8 aB0, half8 aB1, f32x4 (&acc)[2][4])
{
    half8 b00 = *(const half8*)(bb + 0    + swzA);
    half8 b01 = *(const half8*)(bb + 0    + swzB);
    half8 b10 = *(const half8*)(bb + 2048 + swzA);
    half8 b11 = *(const half8*)(bb + 2048 + swzB);
    half8 b20 = *(const half8*)(bb + 4096 + swzA);
    half8 b21 = *(const half8*)(bb + 4096 + swzB);
    half8 b30 = *(const half8*)(bb + 6144 + swzA);
    half8 b31 = *(const half8*)(bb + 6144 + swzB);
    acc[0][0] = __builtin_amdgcn_mfma_f32_16x16x32_f16(aA0, b00, acc[0][0], 0, 0, 0);
    acc[0][0] = __builtin_amdgcn_mfma_f32_16x16x32_f16(aA1, b01, acc[0][0], 0, 0, 0);
    acc[0][1] = __builtin_amdgcn_mfma_f32_16x16x32_f16(aA0, b10, acc[0][1], 0, 0, 0);
    acc[0][1] = __builtin_amdgcn_mfma_f32_16x16x32_f16(aA1, b11, acc[0][1], 0, 0, 0);
    acc[0][2] = __builtin_amdgcn_mfma_f32_16x16x32_f16(aA0, b20, acc[0][2], 0, 0, 0);
    acc[0][2] = __builtin_amdgcn_mfma_f32_16x16x32_f16(aA1, b21, acc[0][2], 0, 0, 0);
    acc[0][3] = __builtin_amdgcn_mfma_f32_16x16x32_f16(aA0, b30, acc[0][3], 0, 0, 0);
    acc[0][3] = __builtin_amdgcn_mfma_f32_16x16x32_f16(aA1, b31, acc[0][3], 0, 0, 0);
    acc[1][0] = __builtin_amdgcn_mfma_f32_16x16x32_f16(aB0, b00, acc[1][0], 0, 0, 0);
    acc[1][0] = __builtin_amdgcn_mfma_f32_16x16x32_f16(aB1, b01, acc[1][0], 0, 0, 0);
    acc[1][1] = __builtin_amdgcn_mfma_f32_16x16x32_f16(aB0, b10, acc[1][1], 0, 0, 0);
    acc[1][1] = __builtin_amdgcn_mfma_f32_16x16x32_f16(aB1, b11, acc[1][1], 0, 0, 0);
    acc[1][2] = __builtin_amdgcn_mfma_f32_16x16x32_f16(aB0, b20, acc[1][2], 0, 0, 0);
    acc[1][2] = __builtin_amdgcn_mfma_f32_16x16x32_f16(aB1, b21, acc[1][2], 0, 0, 0);
    acc[1][3] = __builtin_amdgcn_mfma_f32_16x16x32_f16(aB0, b30, acc[1][3], 0, 0, 0);
    acc[1][3] = __builtin_amdgcn_mfma_f32_16x16x32_f16(aB1, b31, acc[1][3], 0, 0, 0);
}

// 4 waves x 32 edges (2 M-subtiles) — round-7 structure, measured 71us/30% MfmaUtil.
// Round-8 lesson: do NOT trade occupancy for per-wave intensity (latency-bound).
__global__ __launch_bounds__(256) void msg_mfma(
    const f16* __restrict__ h16, const f16* __restrict__ ew16,
    const f16* __restrict__ Wf16, const int* __restrict__ edge_index,
    float* __restrict__ aggr)
{
    __shared__ f16 sh_h[128][72];      // 18432 B
    __shared__ f16 sh_ring[4][4096];   // 32768 B: ew staging, then 4-slab B ring
    __shared__ int sh_dst[128];
    int t = threadIdx.x, lane = t & 63, wv = t >> 6;
    int e0 = blockIdx.x * 128;
    char* ringc = (char*)&sh_ring[0][0];

    const uint4* gW = (const uint4*)Wf16;            // 512 uint4 per 8KB slab
    uint4 r0 = gW[t], r1 = gW[256 + t], r2 = gW[512 + t], r3 = gW[768 + t];

    {   // gather 128 h-rows (padded) + 128 ew-rows (packed+swizzled into ring)
        int row = t >> 1, part = t & 1;
        int e = e0 + row;
        bool valid = e < NE;
        int ec = valid ? e : NE - 1;
        int src = edge_index[ec];
        const uint4* hp = (const uint4*)(h16 + (size_t)src * 64 + part * 32);
        const uint4* ep = (const uint4*)(ew16 + (size_t)ec * 64 + part * 32);
        uint4 z = make_uint4(0u, 0u, 0u, 0u);
        uint4 h0 = hp[0], h1 = hp[1], h2 = hp[2], h3 = hp[3];
        uint4 g0 = valid ? ep[0] : z;
        uint4 g1 = valid ? ep[1] : z;
        uint4 g2 = valid ? ep[2] : z;
        uint4 g3 = valid ? ep[3] : z;
        *(uint4*)&sh_h[row][part * 32]      = h0;
        *(uint4*)&sh_h[row][part * 32 + 8]  = h1;
        *(uint4*)&sh_h[row][part * 32 + 16] = h2;
        *(uint4*)&sh_h[row][part * 32 + 24] = h3;
        int rb = row * 128, key = (row & 7) << 4;
        *(uint4*)(ringc + rb + ((part * 64 +  0) ^ key)) = g0;
        *(uint4*)(ringc + rb + ((part * 64 + 16) ^ key)) = g1;
        *(uint4*)(ringc + rb + ((part * 64 + 32) ^ key)) = g2;
        *(uint4*)(ringc + rb + ((part * 64 + 48) ^ key)) = g3;
        if (lane < 32) {
            int e2 = e0 + wv * 32 + lane;
            sh_dst[wv * 32 + lane] = (e2 < NE) ? edge_index[NE + e2] : -1;
        }
    }

    int r16 = lane & 15, kq = lane >> 4;
    int row0 = wv * 32 + r16, row1 = row0 + 16;

    int k0 = (row0 & 7) << 4, k1 = (row1 & 7) << 4;
    half8 evA0 = *(const half8*)(ringc + row0 * 128 + ((kq * 16) ^ k0));
    half8 evA1 = *(const half8*)(ringc + row0 * 128 + ((64 + kq * 16) ^ k0));
    half8 evB0 = *(const half8*)(ringc + row1 * 128 + ((kq * 16) ^ k1));
    half8 evB1 = *(const half8*)(ringc + row1 * 128 + ((64 + kq * 16) ^ k1));

    __syncthreads();                  // hoists done, ring free, dst visible

    int d0 = t * 16, d1 = 4096 + t * 16;
    int dsw0 = d0 ^ (((d0 >> 7) & 7) << 4);
    int dsw1 = d1 ^ (((d1 >> 7) & 7) << 4);

    *(uint4*)(ringc + dsw0) = r0;
    *(uint4*)(ringc + dsw1) = r1;
    *(uint4*)(ringc + 8192 + dsw0) = r2;
    *(uint4*)(ringc + 8192 + dsw1) = r3;
    r0 = gW[2 * 512 + t]; r1 = gW[2 * 512 + 256 + t];
    r2 = gW[3 * 512 + t]; r3 = gW[3 * 512 + 256 + t];
    __syncthreads();                  // pair0 ready

    f32x4 acc[2][4];
    #pragma unroll
    for (int m = 0; m < 2; ++m)
        #pragma unroll
        for (int n = 0; n < 4; ++n) acc[m][n] = (f32x4){0, 0, 0, 0};

    int swzA = (kq << 4) ^ ((r16 & 7) << 4);
    int swzB = ((kq << 4) | 64) ^ ((r16 & 7) << 4);

    for (int i8 = 0; i8 < 8; ++i8) {
        half8 hA = *(const half8*)&sh_h[row0][i8 * 8];
        half8 hB = *(const half8*)&sh_h[row1][i8 * 8];
        #pragma unroll
        for (int w2 = 0; w2 < 4; ++w2) {
            const char* pairR = ringc + (w2 & 1) * 16384 + r16 * 128;
            #pragma unroll
            for (int s = 0; s < 2; ++s) {
                f16 hsA = hA[w2 * 2 + s];
                f16 hsB = hB[w2 * 2 + s];
                mfma_block(pairR + s * 8192, swzA, swzB,
                           evA0 * splat8(hsA), evA1 * splat8(hsA),
                           evB0 * splat8(hsB), evB1 * splat8(hsB), acc);
            }
            char* wb = ringc + ((w2 + 1) & 1) * 16384;
            *(uint4*)(wb + dsw0) = r0;
            *(uint4*)(wb + dsw1) = r1;
            *(uint4*)(wb + 8192 + dsw0) = r2;
            *(uint4*)(wb + 8192 + dsw1) = r3;
            int jw = i8 * 4 + w2;
            int sA = jw * 2 + 4; if (sA > 64) sA = 64;
            int sB = jw * 2 + 5; if (sB > 64) sB = 64;
            r0 = gW[(size_t)sA * 512 + t]; r1 = gW[(size_t)sA * 512 + 256 + t];
            r2 = gW[(size_t)sB * 512 + t]; r3 = gW[(size_t)sB * 512 + 256 + t];
            __syncthreads();
        }
    }

    {   // bias slab (64): A = h16 rows, B = be3T
        const char* bb = ringc + r16 * 128;
        half8 aA0 = *(const half8*)&sh_h[row0][kq * 8];
        half8 aA1 = *(const half8*)&sh_h[row0][32 + kq * 8];
        half8 aB0 = *(const half8*)&sh_h[row1][kq * 8];
        half8 aB1 = *(const half8*)&sh_h[row1][32 + kq * 8];
        mfma_block(bb, swzA, swzB, aA0, aA1, aB0, aB1, acc);
    }

    #pragma unroll
    for (int m = 0; m < 2; ++m) {
        #pragma unroll
        for (int reg = 0; reg < 4; ++reg) {
            int e_l = wv * 32 + m * 16 + kq * 4 + reg;
            int d = sh_dst[e_l];
            if (d >= 0) {
                float* ap = aggr + (size_t)d * 64 + r16;
                atomicAdd(ap,      acc[m][0][reg]);
                atomicAdd(ap + 16, acc[m][1][reg]);
                atomicAdd(ap + 32, acc[m][2][reg]);
                atomicAdd(ap + 48, acc[m][3][reg]);
            }
        }
    }
}

// ---------------- fused GRU via MFMA: 64 nodes/block, 4 waves ----------------
// m = aggr + cbias + h@root^T (MFMA, C-init from aggr; zeroes aggr in place);
// r/z gates: gi and gh accumulate into the SAME accumulator (sigmoid(i+h));
// n gate split (r multiplies h_n). Weights as B-frags [n_out][k] f16 straight
// from global (48KB, L1-resident). Hidden recursion stays fp32 via hbuf.
__global__ __launch_bounds__(256) void gru_mfma(
    float* __restrict__ aggr, float* __restrict__ hbuf, f16* __restrict__ h16,
    const f16* __restrict__ root16, const float* __restrict__ cbias,
    const f16* __restrict__ Wih16, const f16* __restrict__ Whh16,
    const float* __restrict__ bih, const float* __restrict__ bhh,
    float* __restrict__ out2, int first)
{
    __shared__ f16 sh[64][72];     // h16 rows (A-frags for root & Whh GEMMs)
    __shared__ f16 sm[64][72];     // m rows (f16, A-frags for Wih GEMM)
    int t = threadIdx.x, lane = t & 63, wv = t >> 6;
    int n0 = blockIdx.x * 64;

    {   // stage h rows (masked tail -> zeros)
        int row = t >> 2, part = t & 3;
        int n = n0 + row;
        uint4 z = make_uint4(0u, 0u, 0u, 0u);
        const uint4* hp = (const uint4*)(h16 + (size_t)n * 64 + part * 16);
        uint4 v0 = (n < NN) ? hp[0] : z;
        uint4 v1 = (n < NN) ? hp[1] : z;
        *(uint4*)&sh[row][part * 16]     = v0;
        *(uint4*)&sh[row][part * 16 + 8] = v1;
    }
    __syncthreads();

    int r16 = lane & 15, kq = lane >> 4;
    int wr = wv * 16;
    int rowA = wr + r16;
    half8 ah0 = *(const half8*)&sh[rowA][kq * 8];
    half8 ah1 = *(const half8*)&sh[rowA][32 + kq * 8];
    int nodeBase = wr + kq * 4;       // C/D row = (lane>>4)*4 + reg

    // ---- m = aggr + cbias + h @ root^T ----
    f32x4 accm[4];
    #pragma unroll
    for (int tt = 0; tt < 4; ++tt) {
        int o = tt * 16 + r16;
        float cb = cbias[o];
        #pragma unroll
        for (int reg = 0; reg < 4; ++reg) {
            int n = n0 + nodeBase + reg;
            float v = 0.f;
            if (n < NN) {
                size_t ix = (size_t)n * 64 + o;
                v = aggr[ix] + cb;
                aggr[ix] = 0.f;       // ready for next layer's atomics
            }
            accm[tt][reg] = v;
        }
    }
    #pragma unroll
    for (int tt = 0; tt < 4; ++tt) {
        const f16* bp = root16 + (size_t)(tt * 16 + r16) * 64 + kq * 8;
        half8 b0 = *(const half8*)bp;
        half8 b1 = *(const half8*)(bp + 32);
        accm[tt] = __builtin_amdgcn_mfma_f32_16x16x32_f16(ah0, b0, accm[tt], 0, 0, 0);
        accm[tt] = __builtin_amdgcn_mfma_f32_16x16x32_f16(ah1, b1, accm[tt], 0, 0, 0);
    }
    // scatter m to LDS as f16 rows
    #pragma unroll
    for (int tt = 0; tt < 4; ++tt)
        #pragma unroll
        for (int reg = 0; reg < 4; ++reg)
            sm[nodeBase + reg][tt * 16 + r16] = (f16)accm[tt][reg];
    __syncthreads();
    half8 am0 = *(const half8*)&sm[rowA][kq * 8];
    half8 am1 = *(const half8*)&sm[rowA][32 + kq * 8];

    // ---- gate GEMMs ----
    f32x4 acc_rz[8], acc_in[4], acc_hn[4];
    #pragma unroll
    for (int tt = 0; tt < 8; ++tt) acc_rz[tt] = (f32x4){0, 0, 0, 0};
    #pragma unroll
    for (int tt = 0; tt < 4; ++tt) { acc_in[tt] = (f32x4){0, 0, 0, 0}; acc_hn[tt] = (f32x4){0, 0, 0, 0}; }

    #pragma unroll
    for (int tt = 0; tt < 8; ++tt) {          // r (o 0..63) and z (o 64..127): gi part
        const f16* bp = Wih16 + (size_t)(tt * 16 + r16) * 64 + kq * 8;
        half8 b0 = *(const half8*)bp;
        half8 b1 = *(const half8*)(bp + 32);
        acc_rz[tt] = __builtin_amdgcn_mfma_f32_16x16x32_f16(am0, b0, acc_rz[tt], 0, 0, 0);
        acc_rz[tt] = __builtin_amdgcn_mfma_f32_16x16x32_f16(am1, b1, acc_rz[tt], 0, 0, 0);
    }
    #pragma unroll
    for (int tt = 0; tt < 4; ++tt) {          // i_n (o 128..191)
        const f16* bp = Wih16 + (size_t)(128 + tt * 16 + r16) * 64 + kq * 8;
        half8 b0 = *(const half8*)bp;
        half8 b1 = *(const half8*)(bp + 32);
        acc_in[tt] = __builtin_amdgcn_mfma_f32_16x16x32_f16(am0, b0, acc_in[tt], 0, 0, 0);
        acc_in[tt] = __builtin_amdgcn_mfma_f32_16x16x32_f16(am1, b1, acc_in[tt], 0, 0, 0);
    }
    if (!first) {
        #pragma unroll
        for (int tt = 0; tt < 8; ++tt) {      // gh part sums into same r/z acc
            const f16* bp = Whh16 + (size_t)(tt * 16 + r16) * 64 + kq * 8;
            half8 b0 = *(const half8*)bp;
            half8 b1 = *(const half8*)(bp + 32);
            acc_rz[tt] = __builtin_amdgcn_mfma_f32_16x16x32_f16(ah0, b0, acc_rz[tt], 0, 0, 0);
            acc_rz[tt] = __builtin_amdgcn_mfma_f32_16x16x32_f16(ah1, b1, acc_rz[tt], 0, 0, 0);
        }
        #pragma unroll
        for (int tt = 0; tt < 4; ++tt) {      // h_n separate (r multiplies it)
            const f16* bp = Whh16 + (size_t)(128 + tt * 16 + r16) * 64 + kq * 8;
            half8 b0 = *(const half8*)bp;
            half8 b1 = *(const half8*)(bp + 32);
            acc_hn[tt] = __builtin_amdgcn_mfma_f32_16x16x32_f16(ah0, b0, acc_hn[tt], 0, 0, 0);
            acc_hn[tt] = __builtin_amdgcn_mfma_f32_16x16x32_f16(ah1, b1, acc_hn[tt], 0, 0, 0);
        }
    }

    // ---- gates + store ----
    #pragma unroll
    for (int tt = 0; tt < 4; ++tt) {
        int o = tt * 16 + r16;
        float b_r = bih[o] + bhh[o];
        float b_z = bih[64 + o] + bhh[64 + o];
        float bin = bih[128 + o];
        float bhn = bhh[128 + o];
        #pragma unroll
        for (int reg = 0; reg < 4; ++reg) {
            int n = n0 + nodeBase + reg;
            if (n >= NN) continue;
            size_t ix = (size_t)n * 64 + o;
            float rv = 1.f / (1.f + expf(-(acc_rz[tt][reg] + b_r)));
            float zv = 1.f / (1.f + expf(-(acc_rz[4 + tt][reg] + b_z)));
            float hn_ = first ? bhn : (acc_hn[tt][reg] + bhn);
            float nv = tanhf(acc_in[tt][reg] + bin + rv * hn_);
            float hold = first ? 0.f : hbuf[ix];
            float outv = (1.f - zv) * nv + zv * hold;
            hbuf[ix] = outv;
            h16[ix]  = (f16)outv;
            if (out2) out2[ix] = outv;
        }
    }
}

extern "C" void kernel_launch(void* const* d_in, const int* in_sizes, int n_in,
                              void* d_out, int out_size, void* d_ws, size_t ws_size,
                              hipStream_t stream)
{
    const float* x   = (const float*)d_in[0];
    const float* ea  = (const float*)d_in[1];
    const float* Wn1 = (const float*)d_in[2];  const float* bn1 = (const float*)d_in[3];
    const float* Wn2 = (const float*)d_in[4];  const float* bn2 = (const float*)d_in[5];
    const float* Wn3 = (const float*)d_in[6];  const float* bn3 = (const float*)d_in[7];
    const float* We1 = (const float*)d_in[8];  const float* be1 = (const float*)d_in[9];
    const float* We2 = (const float*)d_in[10]; const float* be2 = (const float*)d_in[11];
    const float* We3 = (const float*)d_in[12]; const float* be3 = (const float*)d_in[13];
    const float* roots = (const float*)d_in[14];
    const float* cb    = (const float*)d_in[15];
    const float* Wih = (const float*)d_in[16]; const float* Whh = (const float*)d_in[17];
    const float* bih = (const float*)d_in[18]; const float* bhh = (const float*)d_in[19];
    const int*   ei  = (const int*)d_in[20];

    // ws layout: fp32 region then fp16 region (16B-aligned)
    float* ws   = (float*)d_ws;
    float* hbuf = ws;                               // N*64
    float* aggr = hbuf + (size_t)NN * 64;           // N*64
    float* Tbuf = aggr + (size_t)NN * 64;           // 15360 (pad to 16384)
    f16*   h16  = (f16*)(ws + 2 * (size_t)NN * 64 + 16384);   // N*64
    f16*   ew16 = h16  + (size_t)NN * 64;                     // E*64
    f16*   Wf16 = ew16 + (size_t)NE * 64;                     // 266240
    f16*   root16 = Wf16 + 266240;                            // 3*4096
    f16*   Wih16  = root16 + 12288;                           // 192*64
    f16*   Whh16  = Wih16 + 12288;                            // 192*64

    prep_all<<<(318464 + 255) / 256, 256, 0, stream>>>(Wn1, Wn2, Wn3, We1, We2,
        Wih, Whh, We3, be3, roots, Tbuf, Wf16, root16, Wih16, Whh16);
    node_mlp<<<(NN + 31) / 32, 256, 0, stream>>>(x, Tbuf, bn1, bn2, bn3,
                                                 hbuf, h16, aggr);
    edge_mlp<<<NE / 32, 256, 0, stream>>>(ea, Tbuf, be1, be2, ew16);

    for (int l = 0; l < 3; ++l) {
        msg_mfma<<<(NE + 127) / 128, 256, 0, stream>>>(h16, ew16, Wf16, ei, aggr);
        gru_mfma<<<(NN + 63) / 64, 256, 0, stream>>>(aggr, hbuf, h16,
            root16 + (size_t)l * 4096, cb + (size_t)l * 64,
            Wih16, Whh16, bih, bhh,
            (l == 2) ? (float*)d_out : nullptr, (l == 0) ? 1 : 0);
    }
}